// Round 1
// baseline (2440.230 us; speedup 1.0000x reference)
//
#include <hip/hip_runtime.h>
#include <cstddef>

#define MDIM 512
#define DDIM 1024
#define BDIM 4096
#define NLAYERS 16

constexpr int BM = 64, BN = 128, BK = 16, TM = 4, TN = 8;
constexpr int NTH = (BM / TM) * (BN / TN);  // 256 threads

__device__ __forceinline__ float softf(float v, float t) {
  // relu(v-t) - relu(-v-t) == copysign(max(|v|-t,0), v)
  return copysignf(fmaxf(fabsf(v) - t, 0.0f), v);
}

// C = P(rows x K, row-major) @ Q(K x BDIM, row-major), fused epilogue.
// MODE 0: layer-0 A-kernel:  t0 = C + E0 - x; Var0 = L0 + beta1[0]*t0
//         O0=Var(ws), O1=E_all[0] (copy E0), O2=L_all[0] (copy L0)
// MODE 1: scan A-kernel (layer k>=1): reads Ep,Lp,x; writes En->O1, Ln->O2, Var->O0
// MODE 2: B-kernel: Zn = soft(Zp - C, ap[k]) -> O0
template <int MODE>
__global__ __launch_bounds__(NTH) void fused_gemm(
    const float* __restrict__ P, const float* __restrict__ Q, int K,
    const float* __restrict__ x, const float* __restrict__ Ep,
    const float* __restrict__ Lp, const float* __restrict__ Zp,
    const float* __restrict__ beta1, const float* __restrict__ beta2,
    const float* __restrict__ beta3, const float* __restrict__ ss2,
    const float* __restrict__ apar, const float* __restrict__ apar1, int k,
    float* __restrict__ O0, float* __restrict__ O1, float* __restrict__ O2) {
  __shared__ __align__(16) float As[BK][BM];   // transposed A tile
  __shared__ __align__(16) float Bs[BK][BN];

  const int tid = threadIdx.x;
  const int m0 = blockIdx.x * BM;
  const int n0 = blockIdx.y * BN;
  const int tn = tid & 15, tm = tid >> 4;

  // staging index maps
  const int arow = tid >> 2;        // 0..63
  const int acol = (tid & 3) * 4;   // 0,4,8,12
  const int brow = tid >> 4;        // 0..15
  const int bcol = (tid & 15) * 8;  // 0..120

  float acc[TM][TN];
#pragma unroll
  for (int i = 0; i < TM; ++i)
#pragma unroll
    for (int j = 0; j < TN; ++j) acc[i][j] = 0.0f;

  const float* pA = &P[(size_t)(m0 + arow) * K + acol];
  const float* pB = &Q[(size_t)brow * BDIM + n0 + bcol];

  for (int k0 = 0; k0 < K; k0 += BK) {
    const float4 av = *reinterpret_cast<const float4*>(pA + k0);
    const float4 bv0 = *reinterpret_cast<const float4*>(pB + (size_t)k0 * BDIM);
    const float4 bv1 = *reinterpret_cast<const float4*>(pB + (size_t)k0 * BDIM + 4);
    __syncthreads();  // prev tile fully consumed before overwrite
    As[acol + 0][arow] = av.x;
    As[acol + 1][arow] = av.y;
    As[acol + 2][arow] = av.z;
    As[acol + 3][arow] = av.w;
    *reinterpret_cast<float4*>(&Bs[brow][bcol]) = bv0;
    *reinterpret_cast<float4*>(&Bs[brow][bcol + 4]) = bv1;
    __syncthreads();
#pragma unroll
    for (int kk = 0; kk < BK; ++kk) {
      const float4 a4 = *reinterpret_cast<const float4*>(&As[kk][tm * TM]);
      const float4 b4 = *reinterpret_cast<const float4*>(&Bs[kk][tn * TN]);
      const float4 b5 = *reinterpret_cast<const float4*>(&Bs[kk][tn * TN + 4]);
      const float a[TM] = {a4.x, a4.y, a4.z, a4.w};
      const float b[TN] = {b4.x, b4.y, b4.z, b4.w, b5.x, b5.y, b5.z, b5.w};
#pragma unroll
      for (int i = 0; i < TM; ++i)
#pragma unroll
        for (int j = 0; j < TN; ++j) acc[i][j] = fmaf(a[i], b[j], acc[i][j]);
    }
  }

  const int row0 = m0 + tm * TM;
  const int col0 = n0 + tn * TN;

  if (MODE == 2) {
    const float ap = apar[k];
#pragma unroll
    for (int i = 0; i < TM; ++i) {
      const size_t off = (size_t)(row0 + i) * BDIM + col0;
      const float4 z0 = *reinterpret_cast<const float4*>(&Zp[off]);
      const float4 z1 = *reinterpret_cast<const float4*>(&Zp[off + 4]);
      float4 o0, o1;
      o0.x = softf(z0.x - acc[i][0], ap);
      o0.y = softf(z0.y - acc[i][1], ap);
      o0.z = softf(z0.z - acc[i][2], ap);
      o0.w = softf(z0.w - acc[i][3], ap);
      o1.x = softf(z1.x - acc[i][4], ap);
      o1.y = softf(z1.y - acc[i][5], ap);
      o1.z = softf(z1.z - acc[i][6], ap);
      o1.w = softf(z1.w - acc[i][7], ap);
      *reinterpret_cast<float4*>(&O0[off]) = o0;
      *reinterpret_cast<float4*>(&O0[off + 4]) = o1;
    }
  } else {
    const float b1v = beta1[k];
    float b2v = 0.f, b3v = 0.f, s2v = 0.f, a1v = 0.f;
    if (MODE == 1) {
      b2v = beta2[k - 1];
      b3v = beta3[k - 1];
      s2v = ss2[k - 1];
      a1v = apar1[k - 1];
    }
#pragma unroll
    for (int i = 0; i < TM; ++i) {
      const size_t off = (size_t)(row0 + i) * BDIM + col0;
      float ev[TN], lv[TN], xv[TN];
      *reinterpret_cast<float4*>(&ev[0]) = *reinterpret_cast<const float4*>(&Ep[off]);
      *reinterpret_cast<float4*>(&ev[4]) = *reinterpret_cast<const float4*>(&Ep[off + 4]);
      *reinterpret_cast<float4*>(&lv[0]) = *reinterpret_cast<const float4*>(&Lp[off]);
      *reinterpret_cast<float4*>(&lv[4]) = *reinterpret_cast<const float4*>(&Lp[off + 4]);
      *reinterpret_cast<float4*>(&xv[0]) = *reinterpret_cast<const float4*>(&x[off]);
      *reinterpret_cast<float4*>(&xv[4]) = *reinterpret_cast<const float4*>(&x[off + 4]);
      float vo[TN], eo[TN], lo_[TN];
#pragma unroll
      for (int j = 0; j < TN; ++j) {
        const float az = acc[i][j];
        if (MODE == 0) {
          const float t0 = az + ev[j] - xv[j];
          vo[j] = fmaf(b1v, t0, lv[j]);
          eo[j] = ev[j];
          lo_[j] = lv[j];
        } else {
          const float vv = fmaf(b2v, az + ev[j] - xv[j], lv[j]);
          const float en = softf(ev[j] - s2v * vv, a1v);
          const float tn_ = az + en - xv[j];
          const float ln = fmaf(b3v, tn_, lv[j]);
          eo[j] = en;
          lo_[j] = ln;
          vo[j] = fmaf(b1v, tn_, ln);
        }
      }
      *reinterpret_cast<float4*>(&O0[off]) = *reinterpret_cast<const float4*>(&vo[0]);
      *reinterpret_cast<float4*>(&O0[off + 4]) = *reinterpret_cast<const float4*>(&vo[4]);
      *reinterpret_cast<float4*>(&O1[off]) = *reinterpret_cast<const float4*>(&eo[0]);
      *reinterpret_cast<float4*>(&O1[off + 4]) = *reinterpret_cast<const float4*>(&eo[4]);
      *reinterpret_cast<float4*>(&O2[off]) = *reinterpret_cast<const float4*>(&lo_[0]);
      *reinterpret_cast<float4*>(&O2[off + 4]) = *reinterpret_cast<const float4*>(&lo_[4]);
    }
  }
}

extern "C" void kernel_launch(void* const* d_in, const int* in_sizes, int n_in,
                              void* d_out, int out_size, void* d_ws,
                              size_t ws_size, hipStream_t stream) {
  (void)in_sizes;
  (void)n_in;
  (void)out_size;
  (void)ws_size;
  const float* x = (const float*)d_in[0];
  const float* A = (const float*)d_in[1];
  const float* W = (const float*)d_in[2];
  const float* Z0 = (const float*)d_in[3];
  const float* E0 = (const float*)d_in[4];
  const float* L0 = (const float*)d_in[5];
  const float* beta1 = (const float*)d_in[6];
  const float* beta2 = (const float*)d_in[7];
  const float* beta3 = (const float*)d_in[8];
  const float* ss2 = (const float*)d_in[9];
  const float* apar = (const float*)d_in[10];
  const float* apar1 = (const float*)d_in[11];

  constexpr size_t DB = (size_t)DDIM * BDIM;  // 1024*4096
  constexpr size_t MB = (size_t)MDIM * BDIM;  // 512*4096
  float* Zall = (float*)d_out;
  float* Eall = Zall + (size_t)NLAYERS * DB;
  float* Lall = Eall + (size_t)NLAYERS * MB;
  float* Var = (float*)d_ws;  // MB floats = 8 MiB

  const dim3 blk(NTH);
  const dim3 g1(MDIM / BM, BDIM / BN);  // 8 x 32  (A@Z -> M x B)
  const dim3 g2(DDIM / BM, BDIM / BN);  // 16 x 32 (W@Var -> D x B)

  // layer 0
  fused_gemm<0><<<g1, blk, 0, stream>>>(A, Z0, DDIM, x, E0, L0, nullptr, beta1,
                                        beta2, beta3, ss2, apar, apar1, 0, Var,
                                        Eall, Lall);
  fused_gemm<2><<<g2, blk, 0, stream>>>(W, Var, MDIM, x, nullptr, nullptr, Z0,
                                        beta1, beta2, beta3, ss2, apar, apar1,
                                        0, Zall, nullptr, nullptr);
  // layers 1..15
  for (int k = 1; k < NLAYERS; ++k) {
    const float* Zp = Zall + (size_t)(k - 1) * DB;
    fused_gemm<1><<<g1, blk, 0, stream>>>(
        A, Zp, DDIM, x, Eall + (size_t)(k - 1) * MB,
        Lall + (size_t)(k - 1) * MB, nullptr, beta1, beta2, beta3, ss2, apar,
        apar1, k, Var, Eall + (size_t)k * MB, Lall + (size_t)k * MB);
    fused_gemm<2><<<g2, blk, 0, stream>>>(
        W + (size_t)k * DDIM * MDIM, Var, MDIM, x, nullptr, nullptr, Zp, beta1,
        beta2, beta3, ss2, apar, apar1, k, Zall + (size_t)k * DB, nullptr,
        nullptr);
  }
}

// Round 5
// 2052.246 us; speedup vs baseline: 1.1891x; 1.1891x over previous
//
#include <hip/hip_runtime.h>
#include <cstddef>

#define MDIM 512
#define DDIM 1024
#define BDIM 4096
#define NLAYERS 16

constexpr int BK = 16;

__device__ __forceinline__ float softf(float v, float t) {
  // relu(v-t) - relu(-v-t) == copysign(max(|v|-t,0), v)
  return copysignf(fmaxf(fabsf(v) - t, 0.0f), v);
}

// ---------------------------------------------------------------------------
// C = P(rows x K, row-major) @ B(K x 4096, row-major), fused epilogue.
// Bit-exact accumulation: per output element one fmaf chain, k ascending —
// identical to the round-1 kernel that passed (absmax 0.2304688).
// Tile: BM=64 x BN (64 or 128), 256 threads, micro-tile 4 x (BN/16) with
// column groups {tn*4 + g*64} (16B lane stride -> conflict-free LDS reads).
// MODE 0: layer-0 A-kernel; MODE 1: scan A-kernel; MODE 2: B-kernel (soft-Z)
// ---------------------------------------------------------------------------
template <int MODE, int K, int BN>
__global__ __launch_bounds__(256) void gemm_f32(
    const float* __restrict__ P, const float* __restrict__ Bm,
    const float* __restrict__ xg, const float* __restrict__ Ep,
    const float* __restrict__ Lp, const float* __restrict__ Zp,
    const float* __restrict__ beta1, const float* __restrict__ beta2,
    const float* __restrict__ beta3, const float* __restrict__ ss2,
    const float* __restrict__ apar, const float* __restrict__ apar1, int k,
    float* __restrict__ O0, float* __restrict__ O1, float* __restrict__ O2) {
  constexpr int TN = BN / 16;  // cols per thread (4 or 8)
  constexpr int NG = BN / 64;  // column groups of 4
  __shared__ __align__(16) float As[2][BK][68];  // padded: write conflicts <=2-way
  __shared__ __align__(16) float Bs[2][BK][BN];

  const int tid = threadIdx.x;
  const int tn = tid & 15, tm = tid >> 4;  // micro-tile coords
  const int m0 = blockIdx.x * 64, n0 = blockIdx.y * BN;

  float acc[4][TN];
#pragma unroll
  for (int r = 0; r < 4; ++r)
#pragma unroll
    for (int c = 0; c < TN; ++c) acc[r][c] = 0.0f;

  // A staging map: thread -> (row ar, k-chunk akc of 4)
  const int ar = tid >> 2, akc = tid & 3;
  const float* gA = P + (size_t)(m0 + ar) * K + akc * 4;
  // B staging map
  const int br = (NG == 1) ? (tid >> 4) : (tid >> 5);
  const int bc = (NG == 1) ? (tid & 15) : (tid & 31);
  const float* gB = Bm + (size_t)br * BDIM + n0 + bc * 4;

  float4 ra, rb0, rb1;
  auto gload = [&](int k0) {
    ra = *reinterpret_cast<const float4*>(gA + (size_t)k0);
    rb0 = *reinterpret_cast<const float4*>(gB + (size_t)k0 * BDIM);
    if (NG == 2)
      rb1 = *reinterpret_cast<const float4*>(gB + (size_t)(k0 + 8) * BDIM);
  };
  auto stagewr = [&](int bb) {
    As[bb][akc * 4 + 0][ar] = ra.x;
    As[bb][akc * 4 + 1][ar] = ra.y;
    As[bb][akc * 4 + 2][ar] = ra.z;
    As[bb][akc * 4 + 3][ar] = ra.w;
    *reinterpret_cast<float4*>(&Bs[bb][br][bc * 4]) = rb0;
    if (NG == 2) *reinterpret_cast<float4*>(&Bs[bb][br + 8][bc * 4]) = rb1;
  };
  auto comp = [&](int bb) {
#pragma unroll
    for (int kk = 0; kk < BK; ++kk) {
      const float4 a4 = *reinterpret_cast<const float4*>(&As[bb][kk][tm * 4]);
      const float a[4] = {a4.x, a4.y, a4.z, a4.w};
      float bv[TN];
#pragma unroll
      for (int g = 0; g < NG; ++g)
        *reinterpret_cast<float4*>(&bv[g * 4]) =
            *reinterpret_cast<const float4*>(&Bs[bb][kk][g * 64 + tn * 4]);
#pragma unroll
      for (int r = 0; r < 4; ++r)
#pragma unroll
        for (int c = 0; c < TN; ++c) acc[r][c] = fmaf(a[r], bv[c], acc[r][c]);
    }
  };

  constexpr int NS = K / BK;
  gload(0);
  stagewr(0);
  __syncthreads();
  int bb = 0;
#pragma unroll 1
  for (int t = 1; t < NS; ++t) {
    gload(t * BK);
    comp(bb);
    stagewr(bb ^ 1);
    __syncthreads();
    bb ^= 1;
  }
  comp(bb);

  // ---- epilogue (expressions identical to round-1 kernel) ----
  const float b1v = (MODE == 2) ? 0.f : beta1[k];
  float b2v = 0.f, b3v = 0.f, s2v = 0.f, a1v = 0.f, ap = 0.f;
  if (MODE == 1) {
    b2v = beta2[k - 1];
    b3v = beta3[k - 1];
    s2v = ss2[k - 1];
    a1v = apar1[k - 1];
  }
  if (MODE == 2) ap = apar[k];

#pragma unroll
  for (int r = 0; r < 4; ++r) {
    const int row = m0 + tm * 4 + r;
#pragma unroll
    for (int g = 0; g < NG; ++g) {
      const int col = n0 + g * 64 + tn * 4;
      const size_t off = (size_t)row * BDIM + col;
      if (MODE == 2) {
        const float4 z4 = *reinterpret_cast<const float4*>(&Zp[off]);
        const float z[4] = {z4.x, z4.y, z4.z, z4.w};
        float4 o;
        float* op = reinterpret_cast<float*>(&o);
#pragma unroll
        for (int j = 0; j < 4; ++j)
          op[j] = softf(z[j] - acc[r][g * 4 + j], ap);
        *reinterpret_cast<float4*>(&O0[off]) = o;
      } else {
        float ev[4], lv[4], xv[4];
        *reinterpret_cast<float4*>(&ev[0]) =
            *reinterpret_cast<const float4*>(&Ep[off]);
        *reinterpret_cast<float4*>(&lv[0]) =
            *reinterpret_cast<const float4*>(&Lp[off]);
        *reinterpret_cast<float4*>(&xv[0]) =
            *reinterpret_cast<const float4*>(&xg[off]);
        float vo[4], eo[4], lo_[4];
#pragma unroll
        for (int j = 0; j < 4; ++j) {
          const float az = acc[r][g * 4 + j];
          if (MODE == 0) {
            const float t0 = az + ev[j] - xv[j];
            vo[j] = fmaf(b1v, t0, lv[j]);
            eo[j] = ev[j];
            lo_[j] = lv[j];
          } else {
            const float vv = fmaf(b2v, az + ev[j] - xv[j], lv[j]);
            const float en = softf(ev[j] - s2v * vv, a1v);
            const float tn_ = az + en - xv[j];
            const float ln = fmaf(b3v, tn_, lv[j]);
            eo[j] = en;
            lo_[j] = ln;
            vo[j] = fmaf(b1v, tn_, ln);
          }
        }
        *reinterpret_cast<float4*>(&O0[off]) =
            *reinterpret_cast<const float4*>(&vo[0]);
        *reinterpret_cast<float4*>(&O1[off]) =
            *reinterpret_cast<const float4*>(&eo[0]);
        *reinterpret_cast<float4*>(&O2[off]) =
            *reinterpret_cast<const float4*>(&lo_[0]);
      }
    }
  }
}

extern "C" void kernel_launch(void* const* d_in, const int* in_sizes, int n_in,
                              void* d_out, int out_size, void* d_ws,
                              size_t ws_size, hipStream_t stream) {
  (void)in_sizes;
  (void)n_in;
  (void)out_size;
  (void)ws_size;
  const float* x = (const float*)d_in[0];
  const float* A = (const float*)d_in[1];
  const float* W = (const float*)d_in[2];
  const float* Z0 = (const float*)d_in[3];
  const float* E0 = (const float*)d_in[4];
  const float* L0 = (const float*)d_in[5];
  const float* beta1 = (const float*)d_in[6];
  const float* beta2 = (const float*)d_in[7];
  const float* beta3 = (const float*)d_in[8];
  const float* ss2 = (const float*)d_in[9];
  const float* apar = (const float*)d_in[10];
  const float* apar1 = (const float*)d_in[11];

  constexpr size_t DB = (size_t)DDIM * BDIM;
  constexpr size_t MB = (size_t)MDIM * BDIM;
  float* Zall = (float*)d_out;
  float* Eall = Zall + (size_t)NLAYERS * DB;
  float* Lall = Eall + (size_t)NLAYERS * MB;
  float* Var = (float*)d_ws;  // MB floats = 8 MiB

  const dim3 blk(256);
  const dim3 gA(MDIM / 64, BDIM / 64);   // 8 x 64  = 512 blocks (BN=64)
  const dim3 gB(DDIM / 64, BDIM / 128);  // 16 x 32 = 512 blocks (BN=128)

  // layer 0
  gemm_f32<0, DDIM, 64><<<gA, blk, 0, stream>>>(
      A, Z0, x, E0, L0, nullptr, beta1, beta2, beta3, ss2, apar, apar1, 0, Var,
      Eall, Lall);
  gemm_f32<2, MDIM, 128><<<gB, blk, 0, stream>>>(
      W, Var, nullptr, nullptr, nullptr, Z0, beta1, beta2, beta3, ss2, apar,
      apar1, 0, Zall, nullptr, nullptr);
  // layers 1..15
  for (int k = 1; k < NLAYERS; ++k) {
    const float* Zp = Zall + (size_t)(k - 1) * DB;
    gemm_f32<1, DDIM, 64><<<gA, blk, 0, stream>>>(
        A, Zp, x, Eall + (size_t)(k - 1) * MB, Lall + (size_t)(k - 1) * MB,
        nullptr, beta1, beta2, beta3, ss2, apar, apar1, k,
        Var, Eall + (size_t)k * MB, Lall + (size_t)k * MB);
    gemm_f32<2, MDIM, 128><<<gB, blk, 0, stream>>>(
        W + (size_t)k * DDIM * MDIM, Var, nullptr, nullptr, nullptr, Zp, beta1,
        beta2, beta3, ss2, apar, apar1, k, Zall + (size_t)k * DB, nullptr,
        nullptr);
  }
}